// Round 13
// baseline (816.606 us; speedup 1.0000x reference)
//
#include <hip/hip_runtime.h>

#define NN 100000
#define NE 1600000
#define NG 512
#define DH 128
#define DH2 256
#define SCB 98      // ceil(NN / 1024)
#define NSTRIPE 32  // stats atomic striping
#define EB4 1563    // ceil(NE/4 / 256)
#define CB 6250     // ceil(NN*16 / 256)
#define WB 512      // wtrans blocks (8 n-tiles x 8 k-tiles x 8 mats)

typedef __attribute__((ext_vector_type(8))) _Float16 h8;  // 8 f16 (4 VGPRs)
typedef __attribute__((ext_vector_type(2))) _Float16 h2;
typedef __attribute__((ext_vector_type(4))) float f4;     // MFMA C/D frag

static inline size_t align256(size_t x) { return (x + 255) & ~size_t(255); }

struct WPack {
    const float* w[8];
    _Float16* wt[8];
    int K[8];
    int N[8];
};

// ---- fused front kernel: 3 disjoint block ranges ------------------------
// [0,EB4):        degree count via NON-RETURNING atomics (R12 insight:
//                 device-scope atomics execute memory-side on MI355X —
//                 returning atomics wait a full fabric round trip; count
//                 doesn't need the old value, so fire-and-forget).
// [EB4,EB4+CB):   x->f16 cast + vfeat init (BW-bound, hides under atomics)
// [EB4+CB,+WB):   weight transpose+cast (independent, saves a launch)
__global__ __launch_bounds__(256) void csrcast_k(
        const int* __restrict__ ei, int* __restrict__ cursor,
        const float* __restrict__ x, _Float16* __restrict__ xh,
        const float* __restrict__ emb, _Float16* __restrict__ vfeat,
        WPack p) {
    __shared__ float t[32][33];
    int b = blockIdx.x;
    if (b < EB4) {
        int i = b * 256 + threadIdx.x;
        int e = i * 4;
        if (e >= NE) return;
        int4 d = *(const int4*)(ei + NE + e);
        atomicAdd(&cursor[d.x], 1);
        atomicAdd(&cursor[d.y], 1);
        atomicAdd(&cursor[d.z], 1);
        atomicAdd(&cursor[d.w], 1);
    } else if (b < EB4 + CB) {
        int i = (b - EB4) * 256 + threadIdx.x;  // NN*16 h8 chunks
        if (i < NG * 16) {
            const float* e = emb + (i & 15) * 8;
            h8 v = {(_Float16)e[0], (_Float16)e[1], (_Float16)e[2], (_Float16)e[3],
                    (_Float16)e[4], (_Float16)e[5], (_Float16)e[6], (_Float16)e[7]};
            ((h8*)vfeat)[i] = v;
        }
        if (i >= NN * 16) return;
        const float4* s = (const float4*)x + i * 2;
        float4 pp = s[0], q = s[1];
        h8 h = {(_Float16)pp.x, (_Float16)pp.y, (_Float16)pp.z, (_Float16)pp.w,
                (_Float16)q.x, (_Float16)q.y, (_Float16)q.z, (_Float16)q.w};
        ((h8*)xh)[i] = h;
    } else {
        int idx = b - (EB4 + CB);
        int id = idx >> 6;
        int rem = idx & 63;
        const float* W = p.w[id];
        _Float16* Wt = p.wt[id];
        int K = p.K[id], N = p.N[id];
        int n0 = (rem & 7) * 32, k0 = (rem >> 3) * 32;
        if (n0 >= N || k0 >= K) return;
        int tx = threadIdx.x & 31, ty = threadIdx.x >> 5;
        for (int i = 0; i < 32; i += 8)
            t[ty + i][tx] = W[(size_t)(k0 + ty + i) * N + n0 + tx];
        __syncthreads();
        for (int i = 0; i < 32; i += 8)
            Wt[(size_t)(n0 + ty + i) * K + k0 + tx] = (_Float16)t[tx][ty + i];
    }
}

// place: position from ONE returning atomic on the mutable rowcur copy
// (edge order within a node is race-determined — order-insensitive sum).
__global__ __launch_bounds__(256) void place_k(const int* __restrict__ ei,
                                               int* __restrict__ rowcur,
                                               int* __restrict__ esrc) {
    int i = blockIdx.x * blockDim.x + threadIdx.x;
    int e = i * 4;
    if (e >= NE) return;
    int4 d = *(const int4*)(ei + NE + e);
    int4 sr = *(const int4*)(ei + e);
    int p0 = atomicAdd(&rowcur[d.x], 1);
    int p1 = atomicAdd(&rowcur[d.y], 1);
    int p2 = atomicAdd(&rowcur[d.z], 1);
    int p3 = atomicAdd(&rowcur[d.w], 1);
    esrc[p0] = sr.x;
    esrc[p1] = sr.y;
    esrc[p2] = sr.z;
    esrc[p3] = sr.w;
}

// 3-kernel device-wide exclusive scan of cursor[NN] -> rowptr (+rowcur copy)
__global__ __launch_bounds__(256) void scan1_k(const int* __restrict__ deg,
                                               int* __restrict__ part) {
    int i0 = blockIdx.x * 1024 + threadIdx.x * 4;
    int s = 0;
    if (i0 < NN) {
        int4 v = *(const int4*)(deg + i0);
        s = v.x + v.y + v.z + v.w;
    }
#pragma unroll
    for (int o = 1; o < 64; o <<= 1) s += __shfl_xor(s, o);
    __shared__ int ws[4];
    if ((threadIdx.x & 63) == 0) ws[threadIdx.x >> 6] = s;
    __syncthreads();
    if (threadIdx.x == 0) part[blockIdx.x] = ws[0] + ws[1] + ws[2] + ws[3];
}

// wave-parallel exclusive scan of part[SCB] + gbound fused
__global__ void scan2_k(int* __restrict__ part, int* __restrict__ rowptr,
                        const int* __restrict__ batch, int* __restrict__ gcnt) {
    int t = threadIdx.x;  // 256 threads
    __shared__ int wtot[2];
    int v = 0, s = 0;
    if (t < 128) {
        v = (t < SCB) ? part[t] : 0;
        s = v;
#pragma unroll
        for (int o = 1; o < 64; o <<= 1) {
            int u = __shfl_up(s, o);
            if ((t & 63) >= o) s += u;
        }
        if ((t & 63) == 63) wtot[t >> 6] = s;
    }
    __syncthreads();
    if (t < 128) {
        if (t >= 64) s += wtot[0];
        if (t < SCB) part[t] = s - v;        // exclusive
        if (t == SCB - 1) rowptr[NN] = s;    // total
    }
    // fused gbound: per-graph node counts via binary search on sorted batch
    for (int g = t; g < NG; g += 256) {
        int lo = 0, hi = NN;
        while (lo < hi) { int m = (lo + hi) >> 1; if (batch[m] < g) lo = m + 1; else hi = m; }
        int b0 = lo;
        lo = 0; hi = NN;
        int g1 = g + 1;
        while (lo < hi) { int m = (lo + hi) >> 1; if (batch[m] < g1) lo = m + 1; else hi = m; }
        gcnt[g] = lo - b0;
    }
}

__global__ __launch_bounds__(256) void scan3_k(const int* __restrict__ deg,
                                               const int* __restrict__ part,
                                               int* __restrict__ rowptr,
                                               int* __restrict__ rowcur) {
    int t = threadIdx.x;
    int i0 = blockIdx.x * 1024 + t * 4;
    int4 v = {0, 0, 0, 0};
    if (i0 < NN) v = *(const int4*)(deg + i0);
    int s = v.x + v.y + v.z + v.w;
    __shared__ int sc[256];
    sc[t] = s;
    __syncthreads();
    for (int o = 1; o < 256; o <<= 1) {
        int add = (t >= o) ? sc[t - o] : 0;
        __syncthreads();
        sc[t] += add;
        __syncthreads();
    }
    int excl = (t ? sc[t - 1] : 0) + part[blockIdx.x];
    if (i0 < NN) {
        int4 r;
        r.x = excl;
        r.y = excl + v.x;
        r.z = r.y + v.y;
        r.w = r.z + v.z;
        *(int4*)(rowptr + i0) = r;
        *(int4*)(rowcur + i0) = r;   // mutable copy for place's atomics
    }
}

// ---- small ops ----------------------------------------------------------
__global__ void zin_k(const float* __restrict__ pooled, const _Float16* __restrict__ vf,
                      _Float16* __restrict__ zb) {
    int i = blockIdx.x * blockDim.x + threadIdx.x;  // NG*DH
    if (i < NG * DH) zb[i] = (_Float16)(pooled[i] + (float)vf[i]);
}

// vn-add streaming pass (R5: fusing into the gather costs more)
__global__ void addvn_k(_Float16* __restrict__ x, const _Float16* __restrict__ vfeat,
                        const int* __restrict__ batch) {
    int i = blockIdx.x * blockDim.x + threadIdx.x;  // NN*16 h8 chunks
    if (i >= NN * 16) return;
    int row = i >> 4;
    int bg = batch[row];
    h8 u = ((h8*)x)[i];
    h8 v = ((const h8*)vfeat)[bg * 16 + (i & 15)];
    h8 o;
#pragma unroll
    for (int e = 0; e < 8; e++) o[e] = (_Float16)((float)u[e] + (float)v[e]);
    ((h8*)x)[i] = o;
}

__global__ void finalout_k(const float* __restrict__ pooled2, const int* __restrict__ gcnt,
                           float* __restrict__ outp) {
    int i = blockIdx.x * blockDim.x + threadIdx.x;
    if (i >= NG * DH) return;
    float cnt = (float)gcnt[i >> 7];
    outp[i] = pooled2[i] / fmaxf(cnt, 1.0f);
}

// ---- aggregation: out[n] = in[n] + sum_j in[src_j]  (f16 rows, f32 acc) -
// EXACT R0 form — minimal inner loop, single full-grid launch.
__global__ __launch_bounds__(256) void agg_k(const _Float16* __restrict__ xin,
                                             const int* __restrict__ rowptr,
                                             const int* __restrict__ esrc,
                                             _Float16* __restrict__ out) {
    int wave = threadIdx.x >> 6, lane = threadIdx.x & 63;
    int node = blockIdx.x * 4 + wave;
    if (node >= NN) return;
    const h2* xr = (const h2*)xin;
    h2 self = xr[(size_t)node * 64 + lane];
    float a0 = (float)self.x, a1 = (float)self.y;
    int beg = rowptr[node], end = rowptr[node + 1];
    int j = beg;
    for (; j + 7 < end; j += 8) {
        int s0 = esrc[j],     s1 = esrc[j + 1], s2 = esrc[j + 2], s3 = esrc[j + 3];
        int s4 = esrc[j + 4], s5 = esrc[j + 5], s6 = esrc[j + 6], s7 = esrc[j + 7];
        h2 u0 = xr[(size_t)s0 * 64 + lane];
        h2 u1 = xr[(size_t)s1 * 64 + lane];
        h2 u2 = xr[(size_t)s2 * 64 + lane];
        h2 u3 = xr[(size_t)s3 * 64 + lane];
        h2 u4 = xr[(size_t)s4 * 64 + lane];
        h2 u5 = xr[(size_t)s5 * 64 + lane];
        h2 u6 = xr[(size_t)s6 * 64 + lane];
        h2 u7 = xr[(size_t)s7 * 64 + lane];
        a0 += ((float)u0.x + (float)u1.x) + ((float)u2.x + (float)u3.x)
            + ((float)u4.x + (float)u5.x) + ((float)u6.x + (float)u7.x);
        a1 += ((float)u0.y + (float)u1.y) + ((float)u2.y + (float)u3.y)
            + ((float)u4.y + (float)u5.y) + ((float)u6.y + (float)u7.y);
    }
    for (; j < end; j++) {
        h2 u = xr[(size_t)esrc[j] * 64 + lane];
        a0 += (float)u.x; a1 += (float)u.y;
    }
    h2 o; o.x = (_Float16)a0; o.y = (_Float16)a1;
    ((h2*)out)[(size_t)node * 64 + lane] = o;
}

// ---- GEMM stats pass: stats(A[Mx128] @ W1 + b) -> striped csum/csq ------
__global__ __launch_bounds__(256, 3) void gemmS_k(
        const _Float16* __restrict__ A, const _Float16* __restrict__ Wt,
        const float* __restrict__ bias,
        float* __restrict__ csum, float* __restrict__ csq, int M) {
    constexpr int K = 128;
    constexpr int LDA = K + 8;   // 136
    __shared__ __align__(16) _Float16 As[64 * LDA];
    __shared__ __align__(16) _Float16 Ws[128 * LDA];
    const int tid = threadIdx.x;
    const int lane = tid & 63;
    const int wave = tid >> 6;
    const int wr = wave >> 1;   // rows wr*32
    const int wc = wave & 1;    // cols wc*64 (within 128-col half)
    const int lm = lane & 15, lq = lane >> 4;
    const int mB = blockIdx.x * 64;

    const int sr = tid >> 4;
    const int sc = (tid & 15) * 8;
#pragma unroll
    for (int rr = 0; rr < 64; rr += 16) {
        int gr = mB + rr + sr; if (gr >= M) gr = M - 1;
        *(h8*)&As[(rr + sr) * LDA + sc] = *(const h8*)&A[(size_t)gr * K + sc];
    }
#pragma unroll
    for (int rr = 0; rr < 128; rr += 16)
        *(h8*)&Ws[(rr + sr) * LDA + sc] = *(const h8*)&Wt[(size_t)(rr + sr) * K + sc];
    __syncthreads();

    f4 acc[2][8];
#pragma unroll
    for (int i = 0; i < 2; i++)
#pragma unroll
        for (int jj = 0; jj < 8; jj++) acc[i][jj] = (f4){0.f, 0.f, 0.f, 0.f};
#pragma unroll
    for (int ct = 0; ct < 2; ct++) {
        if (ct) {
            __syncthreads();
#pragma unroll
            for (int rr = 0; rr < 128; rr += 16)
                *(h8*)&Ws[(rr + sr) * LDA + sc] =
                    *(const h8*)&Wt[(size_t)(128 + rr + sr) * K + sc];
            __syncthreads();
        }
#pragma unroll
        for (int ks = 0; ks < 4; ks++) {
            h8 af[2], bf[4];
#pragma unroll
            for (int i = 0; i < 2; i++)
                af[i] = *(const h8*)&As[(wr * 32 + i * 16 + lm) * LDA + ks * 32 + lq * 8];
#pragma unroll
            for (int j = 0; j < 4; j++)
                bf[j] = *(const h8*)&Ws[(wc * 64 + j * 16 + lm) * LDA + ks * 32 + lq * 8];
#pragma unroll
            for (int i = 0; i < 2; i++)
#pragma unroll
                for (int j = 0; j < 4; j++)
                    acc[i][ct * 4 + j] =
                        __builtin_amdgcn_mfma_f32_16x16x32_f16(af[i], bf[j], acc[i][ct * 4 + j], 0, 0, 0);
        }
    }

    float bv[8];
#pragma unroll
    for (int jj = 0; jj < 8; jj++) bv[jj] = bias[(jj >> 2) * 128 + wc * 64 + (jj & 3) * 16 + lm];
    float ls[8] = {0, 0, 0, 0, 0, 0, 0, 0}, lsq[8] = {0, 0, 0, 0, 0, 0, 0, 0};
#pragma unroll
    for (int i = 0; i < 2; i++) {
        int row = wr * 32 + i * 16 + lq * 4;
#pragma unroll
        for (int jj = 0; jj < 8; jj++) {
#pragma unroll
            for (int r = 0; r < 4; r++) {
                if (mB + row + r < M) {
                    float v = acc[i][jj][r] + bv[jj];
                    ls[jj] += v; lsq[jj] += v * v;
                }
            }
        }
    }
    const int stripe = blockIdx.x & (NSTRIPE - 1);
#pragma unroll
    for (int jj = 0; jj < 8; jj++) {
        float s = ls[jj], q = lsq[jj];
        s += __shfl_xor(s, 16); s += __shfl_xor(s, 32);
        q += __shfl_xor(q, 16); q += __shfl_xor(q, 32);
        if (lq == 0) {
            int col = (jj >> 2) * 128 + wc * 64 + (jj & 3) * 16 + lm;
            atomicAdd(&csum[stripe * 256 + col], s);
            atomicAdd(&csq[stripe * 256 + col], q);
        }
    }
}

// ---- fused GEMM: C = relu(bn(A@W1+b1)) @ W2 + b2  (+ stats for 2nd BN) --
__global__ __launch_bounds__(256, 2) void gemmF_k(
        const _Float16* __restrict__ A,      // x (M x 128)
        const _Float16* __restrict__ Wt1,    // W1^T (256 x 128)
        const _Float16* __restrict__ Wt2,    // W2^T (128 x 256)
        const float* __restrict__ b1v,       // bias1 [256]
        const float* __restrict__ b2v,       // bias2 [128]
        _Float16* __restrict__ C,            // out (M x 128)
        float* __restrict__ csum, float* __restrict__ csq, int M,
        const float* __restrict__ csumIn, const float* __restrict__ csqIn,
        const float* __restrict__ g, const float* __restrict__ b) {
    constexpr int LDA = 136, LDH = 264;
    __shared__ __align__(16) _Float16 Hx[64 * LDH];
    __shared__ __align__(16) _Float16 Ws[128 * LDA];
    __shared__ float s_sc[256], s_sh[256];
    const int tid = threadIdx.x;
    const int lane = tid & 63;
    const int wave = tid >> 6;
    const int wr = wave >> 1;   // rows wr*32
    const int wc = wave & 1;    // cols wc*64
    const int lm = lane & 15, lq = lane >> 4;
    const int mB = blockIdx.x * 64;

    // inline BN1 finalize (stats from gemmS_k)
    {
        float s = 0.f, q = 0.f;
        for (int st = 0; st < NSTRIPE; st++) {
            s += csumIn[st * 256 + tid];
            q += csqIn[st * 256 + tid];
        }
        float invM = 1.0f / (float)M;
        float mean = s * invM;
        float var = q * invM - mean * mean;
        float scv = g[tid] * rsqrtf(var + 1e-5f);
        s_sc[tid] = scv;
        s_sh[tid] = b[tid] - mean * scv;
    }

    const int sr = tid >> 4;
    const int sc = (tid & 15) * 8;
    // phase 1: stage Xs (into Hx region, LDA stride) + W1 half 0
#pragma unroll
    for (int rr = 0; rr < 64; rr += 16) {
        int gr = mB + rr + sr; if (gr >= M) gr = M - 1;
        *(h8*)&Hx[(rr + sr) * LDA + sc] = *(const h8*)&A[(size_t)gr * 128 + sc];
    }
#pragma unroll
    for (int rr = 0; rr < 128; rr += 16)
        *(h8*)&Ws[(rr + sr) * LDA + sc] = *(const h8*)&Wt1[(size_t)(rr + sr) * 128 + sc];
    __syncthreads();

    f4 acc[2][8];
#pragma unroll
    for (int i = 0; i < 2; i++)
#pragma unroll
        for (int jj = 0; jj < 8; jj++) acc[i][jj] = (f4){0.f, 0.f, 0.f, 0.f};
#pragma unroll
    for (int ct = 0; ct < 2; ct++) {
        if (ct) {
            __syncthreads();
#pragma unroll
            for (int rr = 0; rr < 128; rr += 16)
                *(h8*)&Ws[(rr + sr) * LDA + sc] =
                    *(const h8*)&Wt1[(size_t)(128 + rr + sr) * 128 + sc];
            __syncthreads();
        }
#pragma unroll
        for (int ks = 0; ks < 4; ks++) {
            h8 af[2], bf[4];
#pragma unroll
            for (int i = 0; i < 2; i++)
                af[i] = *(const h8*)&Hx[(wr * 32 + i * 16 + lm) * LDA + ks * 32 + lq * 8];
#pragma unroll
            for (int j = 0; j < 4; j++)
                bf[j] = *(const h8*)&Ws[(wc * 64 + j * 16 + lm) * LDA + ks * 32 + lq * 8];
#pragma unroll
            for (int i = 0; i < 2; i++)
#pragma unroll
                for (int j = 0; j < 4; j++)
                    acc[i][ct * 4 + j] =
                        __builtin_amdgcn_mfma_f32_16x16x32_f16(af[i], bf[j], acc[i][ct * 4 + j], 0, 0, 0);
        }
    }
    __syncthreads();  // Xs & Ws consumed

    // write Hs = relu(bn1(h)) into Hx (LDH stride); stage W2 K-slice 0
    {
        float bv1[8];
#pragma unroll
        for (int jj = 0; jj < 8; jj++)
            bv1[jj] = b1v[(jj >> 2) * 128 + wc * 64 + (jj & 3) * 16 + lm];
#pragma unroll
        for (int i = 0; i < 2; i++) {
            int row = wr * 32 + i * 16 + lq * 4;
#pragma unroll
            for (int jj = 0; jj < 8; jj++) {
                int col = (jj >> 2) * 128 + wc * 64 + (jj & 3) * 16 + lm;
                float scv = s_sc[col], shv = s_sh[col];
#pragma unroll
                for (int r = 0; r < 4; r++) {
                    float v = acc[i][jj][r] + bv1[jj];
                    v = fmaxf(v * scv + shv, 0.f);
                    Hx[(row + r) * LDH + col] = (_Float16)v;
                }
            }
        }
    }
#pragma unroll
    for (int rr = 0; rr < 128; rr += 16)
        *(h8*)&Ws[(rr + sr) * LDA + sc] = *(const h8*)&Wt2[(size_t)(rr + sr) * 256 + sc];
    __syncthreads();

    // phase 2: Hs[64x256] @ W2 -> acc2
    f4 acc2[2][4];
#pragma unroll
    for (int i = 0; i < 2; i++)
#pragma unroll
        for (int j = 0; j < 4; j++) acc2[i][j] = (f4){0.f, 0.f, 0.f, 0.f};
#pragma unroll
    for (int kc = 0; kc < 2; kc++) {
        if (kc) {
            __syncthreads();
#pragma unroll
            for (int rr = 0; rr < 128; rr += 16)
                *(h8*)&Ws[(rr + sr) * LDA + sc] =
                    *(const h8*)&Wt2[(size_t)(rr + sr) * 256 + 128 + sc];
            __syncthreads();
        }
#pragma unroll
        for (int ks = 0; ks < 4; ks++) {
            h8 af[2], bf[4];
#pragma unroll
            for (int i = 0; i < 2; i++)
                af[i] = *(const h8*)&Hx[(wr * 32 + i * 16 + lm) * LDH + kc * 128 + ks * 32 + lq * 8];
#pragma unroll
            for (int j = 0; j < 4; j++)
                bf[j] = *(const h8*)&Ws[(wc * 64 + j * 16 + lm) * LDA + ks * 32 + lq * 8];
#pragma unroll
            for (int i = 0; i < 2; i++)
#pragma unroll
                for (int j = 0; j < 4; j++)
                    acc2[i][j] = __builtin_amdgcn_mfma_f32_16x16x32_f16(af[i], bf[j], acc2[i][j], 0, 0, 0);
        }
    }

    // epilogue: Cs through Hx region + 2nd-BN stats
    const int n0 = wc * 64;
    float bv2[4];
#pragma unroll
    for (int j = 0; j < 4; j++) bv2[j] = b2v[n0 + j * 16 + lm];
    float ls[4] = {0, 0, 0, 0}, lsq[4] = {0, 0, 0, 0};
    __syncthreads();  // Hs consumed
    _Float16* Cs = Hx;
#pragma unroll
    for (int i = 0; i < 2; i++) {
        int row = wr * 32 + i * 16 + lq * 4;
        bool rv[4];
#pragma unroll
        for (int r = 0; r < 4; r++) rv[r] = (mB + row + r) < M;
#pragma unroll
        for (int j = 0; j < 4; j++) {
#pragma unroll
            for (int r = 0; r < 4; r++) {
                float v = acc2[i][j][r] + bv2[j];
                Cs[(row + r) * LDA + wc * 64 + j * 16 + lm] = (_Float16)v;
                if (rv[r]) { ls[j] += v; lsq[j] += v * v; }
            }
        }
    }
    const int stripe = blockIdx.x & (NSTRIPE - 1);
#pragma unroll
    for (int j = 0; j < 4; j++) {
        float s = ls[j], q = lsq[j];
        s += __shfl_xor(s, 16); s += __shfl_xor(s, 32);
        q += __shfl_xor(q, 16); q += __shfl_xor(q, 32);
        if (lq == 0) {
            atomicAdd(&csum[stripe * 128 + n0 + j * 16 + lm], s);
            atomicAdd(&csq[stripe * 128 + n0 + j * 16 + lm], q);
        }
    }
    __syncthreads();
    const int trow = tid >> 4;
    const int tcol = (tid & 15) * 8;
#pragma unroll
    for (int p = 0; p < 4; p++) {
        int row = p * 16 + trow;
        int grow = mB + row;
        if (grow < M) {
            h8 v = *(const h8*)&Cs[row * LDA + tcol];
            *(h8*)&C[(size_t)grow * 128 + tcol] = v;
        }
    }
}

// ---- BN apply + relu (+optional vn-add after relu), f16 io, f32 math ----
__global__ void bnrelu_k(const _Float16* __restrict__ in, _Float16* __restrict__ out,
                         const float* __restrict__ csum, const float* __restrict__ csq,
                         const float* __restrict__ g, const float* __restrict__ b,
                         const _Float16* __restrict__ vfeat, const int* __restrict__ batch,
                         int M) {
    constexpr int PER = 16;
    __shared__ float s_sc[128], s_sh[128];
    if (threadIdx.x < 128) {
        int col = threadIdx.x;
        float s = 0.f, q = 0.f;
        for (int st = 0; st < NSTRIPE; st++) {
            s += csum[st * 128 + col];
            q += csq[st * 128 + col];
        }
        float invM = 1.0f / (float)M;
        float mean = s * invM;
        float var = q * invM - mean * mean;
        float scv = g[col] * rsqrtf(var + 1e-5f);
        s_sc[col] = scv;
        s_sh[col] = b[col] - mean * scv;
    }
    __syncthreads();
    int tid = blockIdx.x * blockDim.x + threadIdx.x;
    int c8 = tid % PER;
    int c0 = c8 * 8;
    float sc[8], sh[8];
#pragma unroll
    for (int e = 0; e < 8; e++) { sc[e] = s_sc[c0 + e]; sh[e] = s_sh[c0 + e]; }
    int total = M * PER;
    int stride = gridDim.x * blockDim.x;
    for (int i = tid; i < total; i += stride) {
        int row = i / PER;
        h8 u = ((const h8*)in)[i];
        h8 w;
        bool vn = (vfeat != nullptr);
        if (vn) w = ((const h8*)vfeat)[batch[row] * PER + c8];
        h8 o;
#pragma unroll
        for (int e = 0; e < 8; e++) {
            float vv = fmaxf((float)u[e] * sc[e] + sh[e], 0.f);
            if (vn) vv += (float)w[e];
            o[e] = (_Float16)vv;
        }
        ((h8*)out)[i] = o;
    }
}

// ---- BN apply + segment-sum pool over sorted batch (NC=128) -------------
__global__ __launch_bounds__(256) void bnpool_k(
        const _Float16* __restrict__ in, _Float16* __restrict__ out,
        const float* __restrict__ csum, const float* __restrict__ csq,
        const float* __restrict__ g, const float* __restrict__ b,
        const int* __restrict__ batch, float* __restrict__ pooled,
        int M, int relu) {
    __shared__ float s_sc[128], s_sh[128];
    if (threadIdx.x < 128) {
        int col = threadIdx.x;
        float s = 0.f, q = 0.f;
        for (int st = 0; st < NSTRIPE; st++) {
            s += csum[st * 128 + col];
            q += csq[st * 128 + col];
        }
        float invM = 1.0f / (float)M;
        float mean = s * invM;
        float var = q * invM - mean * mean;
        float scv = g[col] * rsqrtf(var + 1e-5f);
        s_sc[col] = scv;
        s_sh[col] = b[col] - mean * scv;
    }
    __syncthreads();
    int t = threadIdx.x;
    int c0 = (t & 63) * 2;
    int r0 = blockIdx.x * 128 + (t >> 6) * 32;
    float sc0 = s_sc[c0], h0 = s_sh[c0];
    float sc1 = s_sc[c0 + 1], h1 = s_sh[c0 + 1];
    int rend = r0 + 32; if (rend > M) rend = M;
    float a0 = 0.f, a1 = 0.f; int cur = -1;
    int r = r0;
    for (; r + 1 < rend; r += 2) {
        h2 ua = ((const h2*)in)[(size_t)r * 64 + (c0 >> 1)];
        h2 ub = ((const h2*)in)[(size_t)(r + 1) * 64 + (c0 >> 1)];
        int bga = batch[r], bgb = batch[r + 1];
        float va0 = (float)ua.x * sc0 + h0, va1 = (float)ua.y * sc1 + h1;
        float vb0 = (float)ub.x * sc0 + h0, vb1 = (float)ub.y * sc1 + h1;
        if (relu) {
            va0 = fmaxf(va0, 0.f); va1 = fmaxf(va1, 0.f);
            vb0 = fmaxf(vb0, 0.f); vb1 = fmaxf(vb1, 0.f);
        }
        if (out) {
            h2 oa; oa.x = (_Float16)va0; oa.y = (_Float16)va1;
            h2 ob; ob.x = (_Float16)vb0; ob.y = (_Float16)vb1;
            ((h2*)out)[(size_t)r * 64 + (c0 >> 1)] = oa;
            ((h2*)out)[(size_t)(r + 1) * 64 + (c0 >> 1)] = ob;
        }
        if (bga != cur) {
            if (cur >= 0) {
                atomicAdd(&pooled[(size_t)cur * DH + c0], a0);
                atomicAdd(&pooled[(size_t)cur * DH + c0 + 1], a1);
            }
            cur = bga; a0 = 0.f; a1 = 0.f;
        }
        a0 += va0; a1 += va1;
        if (bgb != cur) {
            atomicAdd(&pooled[(size_t)cur * DH + c0], a0);
            atomicAdd(&pooled[(size_t)cur * DH + c0 + 1], a1);
            cur = bgb; a0 = 0.f; a1 = 0.f;
        }
        a0 += vb0; a1 += vb1;
    }
    for (; r < rend; r++) {
        h2 u = ((const h2*)in)[(size_t)r * 64 + (c0 >> 1)];
        float v0 = (float)u.x * sc0 + h0;
        float v1 = (float)u.y * sc1 + h1;
        if (relu) { v0 = fmaxf(v0, 0.f); v1 = fmaxf(v1, 0.f); }
        if (out) { h2 o; o.x = (_Float16)v0; o.y = (_Float16)v1; ((h2*)out)[(size_t)r * 64 + (c0 >> 1)] = o; }
        int bg = batch[r];
        if (bg != cur) {
            if (cur >= 0) {
                atomicAdd(&pooled[(size_t)cur * DH + c0], a0);
                atomicAdd(&pooled[(size_t)cur * DH + c0 + 1], a1);
            }
            cur = bg; a0 = 0.f; a1 = 0.f;
        }
        a0 += v0; a1 += v1;
    }
    if (cur >= 0) {
        atomicAdd(&pooled[(size_t)cur * DH + c0], a0);
        atomicAdd(&pooled[(size_t)cur * DH + c0 + 1], a1);
    }
}

// ------------------------------------------------------------------------
extern "C" void kernel_launch(void* const* d_in, const int* in_sizes, int n_in,
                              void* d_out, int out_size, void* d_ws, size_t ws_size,
                              hipStream_t stream) {
    const float* x      = (const float*)d_in[0];
    const int*   ei     = (const int*)d_in[1];
    const int*   batch  = (const int*)d_in[2];
    const float* vn_emb = (const float*)d_in[3];
    const float* c1_W1  = (const float*)d_in[4];
    const float* c1_b1  = (const float*)d_in[5];
    const float* c1_bng = (const float*)d_in[6];
    const float* c1_bnb = (const float*)d_in[7];
    const float* c1_W2  = (const float*)d_in[8];
    const float* c1_b2  = (const float*)d_in[9];
    const float* bn1_g  = (const float*)d_in[10];
    const float* bn1_b  = (const float*)d_in[11];
    const float* cW1    = (const float*)d_in[12];
    const float* cb1    = (const float*)d_in[13];
    const float* cbng   = (const float*)d_in[14];
    const float* cbnb   = (const float*)d_in[15];
    const float* cW2    = (const float*)d_in[16];
    const float* cb2    = (const float*)d_in[17];
    const float* bns_g  = (const float*)d_in[18];
    const float* bns_b  = (const float*)d_in[19];
    const float* vW1    = (const float*)d_in[20];
    const float* vb1    = (const float*)d_in[21];
    const float* vbn1_g = (const float*)d_in[22];
    const float* vbn1_b = (const float*)d_in[23];
    const float* vW2    = (const float*)d_in[24];
    const float* vb2    = (const float*)d_in[25];
    const float* vbn2_g = (const float*)d_in[26];
    const float* vbn2_b = (const float*)d_in[27];
    float* outp = (float*)d_out;
    (void)in_sizes; (void)n_in; (void)out_size; (void)ws_size;

    char* w = (char*)d_ws;
    size_t off = 0;
    auto carve = [&](size_t bytes) -> void* {
        void* p = w + off; off = align256(off + bytes); return p;
    };
    // zero-init region
    int*   cursor  = (int*)carve((size_t)NN * 4);
    float* pooled  = (float*)carve((size_t)NG * DH * 4);
    float* pooled2 = (float*)carve((size_t)NG * DH * 4);
    float *sA[3], *qA[3], *sB[3], *qB[3], *sV1, *qV1, *sV2, *qV2;
    for (int i = 0; i < 3; i++) {
        sA[i] = (float*)carve((size_t)NSTRIPE * 256 * 4);
        qA[i] = (float*)carve((size_t)NSTRIPE * 256 * 4);
    }
    for (int i = 0; i < 3; i++) {
        sB[i] = (float*)carve((size_t)NSTRIPE * 128 * 4);
        qB[i] = (float*)carve((size_t)NSTRIPE * 128 * 4);
    }
    sV1 = (float*)carve((size_t)NSTRIPE * 256 * 4);
    qV1 = (float*)carve((size_t)NSTRIPE * 256 * 4);
    sV2 = (float*)carve((size_t)NSTRIPE * 128 * 4);
    qV2 = (float*)carve((size_t)NSTRIPE * 128 * 4);
    size_t zbytes = off;
    // non-zeroed region
    int*   gcnt    = (int*)carve((size_t)NG * 4);
    int*   rowptr  = (int*)carve((size_t)(NN + 1) * 4);
    int*   rowcur  = (int*)carve((size_t)NN * 4);
    int*   esrc    = (int*)carve((size_t)NE * 4);
    int*   part    = (int*)carve((size_t)SCB * 4);
    _Float16* vfeat = (_Float16*)carve((size_t)NG * DH * 2);
    _Float16* zin   = (_Float16*)carve((size_t)NG * DH * 2);
    _Float16* vraw  = (_Float16*)carve((size_t)NG * DH * 2);
    _Float16* xh    = (_Float16*)carve((size_t)NN * DH * 2);
    _Float16* hb    = (_Float16*)carve((size_t)NN * DH * 2);
    _Float16* abuf  = (_Float16*)carve((size_t)NN * DH * 2);
    _Float16* Wt[8];
    for (int i = 0; i < 8; i++) Wt[i] = (_Float16*)carve((size_t)DH * DH2 * 2);

    WPack wp;
    wp.w[0] = c1_W1;            wp.K[0] = 128; wp.N[0] = 256;
    wp.w[1] = c1_W2;            wp.K[1] = 256; wp.N[1] = 128;
    wp.w[2] = cW1;              wp.K[2] = 128; wp.N[2] = 256;
    wp.w[3] = cW2;              wp.K[3] = 256; wp.N[3] = 128;
    wp.w[4] = cW1 + 128 * 256;  wp.K[4] = 128; wp.N[4] = 256;
    wp.w[5] = cW2 + 256 * 128;  wp.K[5] = 256; wp.N[5] = 128;
    wp.w[6] = vW1;              wp.K[6] = 128; wp.N[6] = 256;
    wp.w[7] = vW2;              wp.K[7] = 256; wp.N[7] = 128;
    for (int i = 0; i < 8; i++) wp.wt[i] = Wt[i];

    const int GB64 = (NN + 63) / 64;   // 1563
    const int GB   = (NN + 127) / 128; // 782 (bnpool grid)
    const int GV64 = (NG + 63) / 64;   // 8

    hipMemsetAsync(d_ws, 0, zbytes, stream);
    csrcast_k<<<EB4 + CB + WB, 256, 0, stream>>>(ei, cursor, x, xh, vn_emb, vfeat, wp);
    scan1_k<<<SCB, 256, 0, stream>>>(cursor, part);
    scan2_k<<<1, 256, 0, stream>>>(part, rowptr, batch, gcnt);
    scan3_k<<<SCB, 256, 0, stream>>>(cursor, part, rowptr, rowcur);
    place_k<<<EB4, 256, 0, stream>>>(ei, rowcur, esrc);

    // ---- layer 1 ----
    agg_k<<<NN / 4, 256, 0, stream>>>(xh, rowptr, esrc, hb);
    gemmS_k<<<GB64, 256, 0, stream>>>(hb, Wt[0], c1_b1, sA[0], qA[0], NN);
    gemmF_k<<<GB64, 256, 0, stream>>>(hb, Wt[0], Wt[1], c1_b1, c1_b2, abuf,
                                      sB[0], qB[0], NN, sA[0], qA[0], c1_bng, c1_bnb);
    bnrelu_k<<<2048, 256, 0, stream>>>(abuf, abuf, sB[0], qB[0], bn1_g, bn1_b,
                                       vfeat, batch, NN);

    // ---- layer 2 ----
    agg_k<<<NN / 4, 256, 0, stream>>>(abuf, rowptr, esrc, hb);
    gemmS_k<<<GB64, 256, 0, stream>>>(hb, Wt[2], cb1, sA[1], qA[1], NN);
    gemmF_k<<<GB64, 256, 0, stream>>>(hb, Wt[2], Wt[3], cb1, cb2, abuf,
                                      sB[1], qB[1], NN, sA[1], qA[1], cbng, cbnb);
    bnpool_k<<<GB, 256, 0, stream>>>(abuf, abuf, sB[1], qB[1], bns_g, bns_b,
                                     batch, pooled, NN, 1);

    // ---- virtual-node MLP (M = 512) ----
    zin_k<<<(NG * DH + 255) / 256, 256, 0, stream>>>(pooled, vfeat, zin);
    gemmS_k<<<GV64, 256, 0, stream>>>(zin, Wt[6], vb1, sV1, qV1, NG);
    gemmF_k<<<GV64, 256, 0, stream>>>(zin, Wt[6], Wt[7], vb1, vb2, vraw,
                                      sV2, qV2, NG, sV1, qV1, vbn1_g, vbn1_b);
    bnrelu_k<<<32, 256, 0, stream>>>(vraw, vfeat, sV2, qV2, vbn2_g, vbn2_b,
                                     nullptr, nullptr, NG);

    // ---- layer 3 (vn-add as separate streaming pass) ----
    addvn_k<<<(NN * 16 + 255) / 256, 256, 0, stream>>>(abuf, vfeat, batch);
    agg_k<<<NN / 4, 256, 0, stream>>>(abuf, rowptr, esrc, hb);
    gemmS_k<<<GB64, 256, 0, stream>>>(hb, Wt[4], cb1 + 256, sA[2], qA[2], NN);
    gemmF_k<<<GB64, 256, 0, stream>>>(hb, Wt[4], Wt[5], cb1 + 256, cb2 + 128, abuf,
                                      sB[2], qB[2], NN, sA[2], qA[2], cbng + 256, cbnb + 256);
    bnpool_k<<<GB, 256, 0, stream>>>(abuf, nullptr, sB[2], qB[2],
                                     bns_g + 128, bns_b + 128, batch, pooled2, NN, 0);

    finalout_k<<<(NG * DH + 255) / 256, 256, 0, stream>>>(pooled2, gcnt, outp);
}

// Round 14
// 685.053 us; speedup vs baseline: 1.1920x; 1.1920x over previous
//
#include <hip/hip_runtime.h>

#define NN 100000
#define NE 1600000
#define NG 512
#define DH 128
#define DH2 256
#define SCB 98      // ceil(NN / 1024)
#define NSTRIPE 32  // stats atomic striping
#define EB4 1563    // ceil(NE/4 / 256)
#define CB 6250     // ceil(NN*16 / 256)
#define WB 512      // wtrans blocks (8 n-tiles x 8 k-tiles x 8 mats)

typedef __attribute__((ext_vector_type(8))) _Float16 h8;  // 8 f16 (4 VGPRs)
typedef __attribute__((ext_vector_type(2))) _Float16 h2;
typedef __attribute__((ext_vector_type(4))) float f4;     // MFMA C/D frag

static inline size_t align256(size_t x) { return (x + 255) & ~size_t(255); }

struct WPack {
    const float* w[8];
    _Float16* wt[8];
    int K[8];
    int N[8];
};

// ---- fused front kernel: 3 disjoint block ranges ------------------------
// [0,EB4):        4-way-striped RETURNING atomic count + slot store (the
//                 ~70us round-trip cost is a memory-side HW floor, R10-R13;
//                 the slot trick keeps place dependency-free)
// [EB4,EB4+CB):   x->f16 cast + vfeat init (hides under the atomic phase)
// [EB4+CB,+WB):   weight transpose+cast
__global__ __launch_bounds__(256) void csrcast_k(
        const int* __restrict__ ei, int* __restrict__ cursor, int* __restrict__ slot,
        const float* __restrict__ x, _Float16* __restrict__ xh,
        const float* __restrict__ emb, _Float16* __restrict__ vfeat,
        WPack p) {
    __shared__ float t[32][33];
    int b = blockIdx.x;
    if (b < EB4) {
        int i = b * 256 + threadIdx.x;
        int e = i * 4;
        if (e >= NE) return;
        int4 d = *(const int4*)(ei + NE + e);
        int s0 = atomicAdd(&cursor[0 * NN + d.x], 1);
        int s1 = atomicAdd(&cursor[1 * NN + d.y], 1);
        int s2 = atomicAdd(&cursor[2 * NN + d.z], 1);
        int s3 = atomicAdd(&cursor[3 * NN + d.w], 1);
        int4 r; r.x = s0; r.y = s1; r.z = s2; r.w = s3;
        *(int4*)(slot + e) = r;
    } else if (b < EB4 + CB) {
        int i = (b - EB4) * 256 + threadIdx.x;  // NN*16 h8 chunks
        if (i < NG * 16) {
            const float* e = emb + (i & 15) * 8;
            h8 v = {(_Float16)e[0], (_Float16)e[1], (_Float16)e[2], (_Float16)e[3],
                    (_Float16)e[4], (_Float16)e[5], (_Float16)e[6], (_Float16)e[7]};
            ((h8*)vfeat)[i] = v;
        }
        if (i >= NN * 16) return;
        const float4* s = (const float4*)x + i * 2;
        float4 pp = s[0], q = s[1];
        h8 h = {(_Float16)pp.x, (_Float16)pp.y, (_Float16)pp.z, (_Float16)pp.w,
                (_Float16)q.x, (_Float16)q.y, (_Float16)q.z, (_Float16)q.w};
        ((h8*)xh)[i] = h;
    } else {
        int idx = b - (EB4 + CB);
        int id = idx >> 6;
        int rem = idx & 63;
        const float* W = p.w[id];
        _Float16* Wt = p.wt[id];
        int K = p.K[id], N = p.N[id];
        int n0 = (rem & 7) * 32, k0 = (rem >> 3) * 32;
        if (n0 >= N || k0 >= K) return;
        int tx = threadIdx.x & 31, ty = threadIdx.x >> 5;
        for (int i = 0; i < 32; i += 8)
            t[ty + i][tx] = W[(size_t)(k0 + ty + i) * N + n0 + tx];
        __syncthreads();
        for (int i = 0; i < 32; i += 8)
            Wt[(size_t)(n0 + ty + i) * K + k0 + tx] = (_Float16)t[tx][ty + i];
    }
}

// place: position = rowbase[stripe][dst] + slot (stripe = e&3); pure
// gather+scatter, no atomics (R13 lesson: atomic-return -> dependent
// scatter serializes; keep them in separate passes)
__global__ __launch_bounds__(256) void place_k(const int* __restrict__ ei,
                                               const int* __restrict__ rowbase,
                                               const int* __restrict__ slot,
                                               int* __restrict__ esrc) {
    int i = blockIdx.x * blockDim.x + threadIdx.x;
    int e = i * 4;
    if (e >= NE) return;
    int4 d = *(const int4*)(ei + NE + e);
    int4 sl = *(const int4*)(slot + e);
    int4 sr = *(const int4*)(ei + e);
    int r0 = rowbase[0 * NN + d.x];
    int r1 = rowbase[1 * NN + d.y];
    int r2 = rowbase[2 * NN + d.z];
    int r3 = rowbase[3 * NN + d.w];
    esrc[r0 + sl.x] = sr.x;
    esrc[r1 + sl.y] = sr.y;
    esrc[r2 + sl.z] = sr.z;
    esrc[r3 + sl.w] = sr.w;
}

// 3-kernel device-wide exclusive scan of striped cursor -> rowptr (+rowbase)
__global__ __launch_bounds__(256) void scan1_k(const int* __restrict__ cur,
                                               int* __restrict__ part) {
    int i0 = blockIdx.x * 1024 + threadIdx.x * 4;
    int s = 0;
    if (i0 < NN) {
        int4 a = *(const int4*)(cur + i0);
        int4 b = *(const int4*)(cur + NN + i0);
        int4 c = *(const int4*)(cur + 2 * NN + i0);
        int4 d = *(const int4*)(cur + 3 * NN + i0);
        s = (a.x + a.y + a.z + a.w) + (b.x + b.y + b.z + b.w)
          + (c.x + c.y + c.z + c.w) + (d.x + d.y + d.z + d.w);
    }
#pragma unroll
    for (int o = 1; o < 64; o <<= 1) s += __shfl_xor(s, o);
    __shared__ int ws[4];
    if ((threadIdx.x & 63) == 0) ws[threadIdx.x >> 6] = s;
    __syncthreads();
    if (threadIdx.x == 0) part[blockIdx.x] = ws[0] + ws[1] + ws[2] + ws[3];
}

// wave-parallel exclusive scan of part[SCB] + gbound fused
__global__ void scan2_k(int* __restrict__ part, int* __restrict__ rowptr,
                        const int* __restrict__ batch, int* __restrict__ gcnt) {
    int t = threadIdx.x;  // 256 threads
    __shared__ int wtot[2];
    int v = 0, s = 0;
    if (t < 128) {
        v = (t < SCB) ? part[t] : 0;
        s = v;
#pragma unroll
        for (int o = 1; o < 64; o <<= 1) {
            int u = __shfl_up(s, o);
            if ((t & 63) >= o) s += u;
        }
        if ((t & 63) == 63) wtot[t >> 6] = s;
    }
    __syncthreads();
    if (t < 128) {
        if (t >= 64) s += wtot[0];
        if (t < SCB) part[t] = s - v;        // exclusive
        if (t == SCB - 1) rowptr[NN] = s;    // total
    }
    // fused gbound: per-graph node counts via binary search on sorted batch
    for (int g = t; g < NG; g += 256) {
        int lo = 0, hi = NN;
        while (lo < hi) { int m = (lo + hi) >> 1; if (batch[m] < g) lo = m + 1; else hi = m; }
        int b0 = lo;
        lo = 0; hi = NN;
        int g1 = g + 1;
        while (lo < hi) { int m = (lo + hi) >> 1; if (batch[m] < g1) lo = m + 1; else hi = m; }
        gcnt[g] = lo - b0;
    }
}

__global__ __launch_bounds__(256) void scan3_k(const int* __restrict__ cur,
                                               const int* __restrict__ part,
                                               int* __restrict__ rowptr,
                                               int* __restrict__ rowbase) {
    int t = threadIdx.x;
    int i0 = blockIdx.x * 1024 + t * 4;
    int4 c0 = {0,0,0,0}, c1 = {0,0,0,0}, c2 = {0,0,0,0}, c3 = {0,0,0,0};
    if (i0 < NN) {
        c0 = *(const int4*)(cur + i0);
        c1 = *(const int4*)(cur + NN + i0);
        c2 = *(const int4*)(cur + 2 * NN + i0);
        c3 = *(const int4*)(cur + 3 * NN + i0);
    }
    int4 tot;
    tot.x = c0.x + c1.x + c2.x + c3.x;
    tot.y = c0.y + c1.y + c2.y + c3.y;
    tot.z = c0.z + c1.z + c2.z + c3.z;
    tot.w = c0.w + c1.w + c2.w + c3.w;
    int s = tot.x + tot.y + tot.z + tot.w;
    __shared__ int sc[256];
    sc[t] = s;
    __syncthreads();
    for (int o = 1; o < 256; o <<= 1) {
        int add = (t >= o) ? sc[t - o] : 0;
        __syncthreads();
        sc[t] += add;
        __syncthreads();
    }
    int excl = (t ? sc[t - 1] : 0) + part[blockIdx.x];
    if (i0 < NN) {
        int4 r;
        r.x = excl;
        r.y = excl + tot.x;
        r.z = r.y + tot.y;
        r.w = r.z + tot.z;
        *(int4*)(rowptr + i0) = r;
        // rowbase[k][n] = rowptr[n] + sum_{k'<k} cnt[k'][n]
        *(int4*)(rowbase + i0) = r;
        int4 b1v; b1v.x = r.x + c0.x; b1v.y = r.y + c0.y; b1v.z = r.z + c0.z; b1v.w = r.w + c0.w;
        *(int4*)(rowbase + NN + i0) = b1v;
        int4 b2v; b2v.x = b1v.x + c1.x; b2v.y = b1v.y + c1.y; b2v.z = b1v.z + c1.z; b2v.w = b1v.w + c1.w;
        *(int4*)(rowbase + 2 * NN + i0) = b2v;
        int4 b3v; b3v.x = b2v.x + c2.x; b3v.y = b2v.y + c2.y; b3v.z = b2v.z + c2.z; b3v.w = b2v.w + c2.w;
        *(int4*)(rowbase + 3 * NN + i0) = b3v;
    }
}

// ---- small ops ----------------------------------------------------------
__global__ void zin_k(const float* __restrict__ pooled, const _Float16* __restrict__ vf,
                      _Float16* __restrict__ zb) {
    int i = blockIdx.x * blockDim.x + threadIdx.x;  // NG*DH
    if (i < NG * DH) zb[i] = (_Float16)(pooled[i] + (float)vf[i]);
}

// vn-add streaming pass (R5: fusing into the gather costs more)
__global__ void addvn_k(_Float16* __restrict__ x, const _Float16* __restrict__ vfeat,
                        const int* __restrict__ batch) {
    int i = blockIdx.x * blockDim.x + threadIdx.x;  // NN*16 h8 chunks
    if (i >= NN * 16) return;
    int row = i >> 4;
    int bg = batch[row];
    h8 u = ((h8*)x)[i];
    h8 v = ((const h8*)vfeat)[bg * 16 + (i & 15)];
    h8 o;
#pragma unroll
    for (int e = 0; e < 8; e++) o[e] = (_Float16)((float)u[e] + (float)v[e]);
    ((h8*)x)[i] = o;
}

__global__ void finalout_k(const float* __restrict__ pooled2, const int* __restrict__ gcnt,
                           float* __restrict__ outp) {
    int i = blockIdx.x * blockDim.x + threadIdx.x;
    if (i >= NG * DH) return;
    float cnt = (float)gcnt[i >> 7];
    outp[i] = pooled2[i] / fmaxf(cnt, 1.0f);
}

// ---- aggregation: out[n] = in[n] + sum_j in[src_j]  (f16 rows, f32 acc) -
// EXACT R0 form — minimal inner loop, single full-grid launch.
__global__ __launch_bounds__(256) void agg_k(const _Float16* __restrict__ xin,
                                             const int* __restrict__ rowptr,
                                             const int* __restrict__ esrc,
                                             _Float16* __restrict__ out) {
    int wave = threadIdx.x >> 6, lane = threadIdx.x & 63;
    int node = blockIdx.x * 4 + wave;
    if (node >= NN) return;
    const h2* xr = (const h2*)xin;
    h2 self = xr[(size_t)node * 64 + lane];
    float a0 = (float)self.x, a1 = (float)self.y;
    int beg = rowptr[node], end = rowptr[node + 1];
    int j = beg;
    for (; j + 7 < end; j += 8) {
        int s0 = esrc[j],     s1 = esrc[j + 1], s2 = esrc[j + 2], s3 = esrc[j + 3];
        int s4 = esrc[j + 4], s5 = esrc[j + 5], s6 = esrc[j + 6], s7 = esrc[j + 7];
        h2 u0 = xr[(size_t)s0 * 64 + lane];
        h2 u1 = xr[(size_t)s1 * 64 + lane];
        h2 u2 = xr[(size_t)s2 * 64 + lane];
        h2 u3 = xr[(size_t)s3 * 64 + lane];
        h2 u4 = xr[(size_t)s4 * 64 + lane];
        h2 u5 = xr[(size_t)s5 * 64 + lane];
        h2 u6 = xr[(size_t)s6 * 64 + lane];
        h2 u7 = xr[(size_t)s7 * 64 + lane];
        a0 += ((float)u0.x + (float)u1.x) + ((float)u2.x + (float)u3.x)
            + ((float)u4.x + (float)u5.x) + ((float)u6.x + (float)u7.x);
        a1 += ((float)u0.y + (float)u1.y) + ((float)u2.y + (float)u3.y)
            + ((float)u4.y + (float)u5.y) + ((float)u6.y + (float)u7.y);
    }
    for (; j < end; j++) {
        h2 u = xr[(size_t)esrc[j] * 64 + lane];
        a0 += (float)u.x; a1 += (float)u.y;
    }
    h2 o; o.x = (_Float16)a0; o.y = (_Float16)a1;
    ((h2*)out)[(size_t)node * 64 + lane] = o;
}

// ---- GEMM1: C[M x 256] = A[M x 128] @ W + bias (R8 form, 64-row tiles) --
__global__ __launch_bounds__(256, 3) void gemmA_k(
        const _Float16* __restrict__ A, const _Float16* __restrict__ Wt,
        const float* __restrict__ bias, _Float16* __restrict__ C,
        float* __restrict__ csum, float* __restrict__ csq, int M) {
    constexpr int K = 128, NCF = 256;
    constexpr int LDA = K + 8;   // 136
    __shared__ __align__(16) _Float16 As[64 * LDA];
    __shared__ __align__(16) _Float16 Ws[128 * LDA];
    const int tid = threadIdx.x;
    const int lane = tid & 63;
    const int wave = tid >> 6;
    const int wr = wave >> 1;   // rows wr*32
    const int wc = wave & 1;    // cols wc*64 (within 128-col half)
    const int lm = lane & 15, lq = lane >> 4;
    const int mB = blockIdx.x * 64;

    const int sr = tid >> 4;          // 0..15
    const int sc = (tid & 15) * 8;
#pragma unroll
    for (int rr = 0; rr < 64; rr += 16) {
        int gr = mB + rr + sr; if (gr >= M) gr = M - 1;
        *(h8*)&As[(rr + sr) * LDA + sc] = *(const h8*)&A[(size_t)gr * K + sc];
    }
#pragma unroll
    for (int rr = 0; rr < 128; rr += 16)
        *(h8*)&Ws[(rr + sr) * LDA + sc] = *(const h8*)&Wt[(size_t)(rr + sr) * K + sc];
    __syncthreads();

    f4 acc[2][8];
#pragma unroll
    for (int i = 0; i < 2; i++)
#pragma unroll
        for (int jj = 0; jj < 8; jj++) acc[i][jj] = (f4){0.f, 0.f, 0.f, 0.f};
#pragma unroll
    for (int ct = 0; ct < 2; ct++) {
        if (ct) {
            __syncthreads();
#pragma unroll
            for (int rr = 0; rr < 128; rr += 16)
                *(h8*)&Ws[(rr + sr) * LDA + sc] =
                    *(const h8*)&Wt[(size_t)(128 + rr + sr) * K + sc];
            __syncthreads();
        }
#pragma unroll
        for (int ks = 0; ks < 4; ks++) {
            h8 af[2], bf[4];
#pragma unroll
            for (int i = 0; i < 2; i++)
                af[i] = *(const h8*)&As[(wr * 32 + i * 16 + lm) * LDA + ks * 32 + lq * 8];
#pragma unroll
            for (int j = 0; j < 4; j++)
                bf[j] = *(const h8*)&Ws[(wc * 64 + j * 16 + lm) * LDA + ks * 32 + lq * 8];
#pragma unroll
            for (int i = 0; i < 2; i++)
#pragma unroll
                for (int j = 0; j < 4; j++)
                    acc[i][ct * 4 + j] =
                        __builtin_amdgcn_mfma_f32_16x16x32_f16(af[i], bf[j], acc[i][ct * 4 + j], 0, 0, 0);
        }
    }

    float bv[8];
#pragma unroll
    for (int jj = 0; jj < 8; jj++) bv[jj] = bias[(jj >> 2) * 128 + wc * 64 + (jj & 3) * 16 + lm];
    float ls[8] = {0, 0, 0, 0, 0, 0, 0, 0}, lsq[8] = {0, 0, 0, 0, 0, 0, 0, 0};
    _Float16* Cs = As;
    const int trow = tid >> 4;
    const int tcol = (tid & 15) * 8;
#pragma unroll
    for (int half = 0; half < 2; half++) {
        __syncthreads();
#pragma unroll
        for (int i = 0; i < 2; i++) {
            int row = wr * 32 + i * 16 + lq * 4;
#pragma unroll
            for (int j = 0; j < 4; j++) {
                int jj = half * 4 + j;
#pragma unroll
                for (int r = 0; r < 4; r++) {
                    float v = acc[i][jj][r] + bv[jj];
                    Cs[(row + r) * LDA + wc * 64 + j * 16 + lm] = (_Float16)v;
                    if (mB + row + r < M) { ls[jj] += v; lsq[jj] += v * v; }
                }
            }
        }
        __syncthreads();
#pragma unroll
        for (int p = 0; p < 4; p++) {
            int row = p * 16 + trow;
            int grow = mB + row;
            if (grow < M) {
                h8 v = *(const h8*)&Cs[row * LDA + tcol];
                *(h8*)&C[(size_t)grow * NCF + half * 128 + tcol] = v;
            }
        }
    }
    const int stripe = blockIdx.x & (NSTRIPE - 1);
#pragma unroll
    for (int jj = 0; jj < 8; jj++) {
        float s = ls[jj], q = lsq[jj];
        s += __shfl_xor(s, 16); s += __shfl_xor(s, 32);
        q += __shfl_xor(q, 16); q += __shfl_xor(q, 32);
        if (lq == 0) {
            int col = (jj >> 2) * 128 + wc * 64 + (jj & 3) * 16 + lm;
            atomicAdd(&csum[stripe * NCF + col], s);
            atomicAdd(&csq[stripe * NCF + col], q);
        }
    }
}

// ---- GEMM2: C[M x 128] = relu(bn(A))[M x 256] @ W + bias (R8 form) ------
__global__ __launch_bounds__(256, 3) void gemmB_k(
        const _Float16* __restrict__ A, const _Float16* __restrict__ Wt,
        const float* __restrict__ bias, _Float16* __restrict__ C,
        float* __restrict__ csum, float* __restrict__ csq, int M,
        const float* __restrict__ csumIn, const float* __restrict__ csqIn,
        const float* __restrict__ g, const float* __restrict__ b) {
    constexpr int K = 256, NCF = 128, BK = 128;
    constexpr int LDA = BK + 8;   // 136 (As)
    constexpr int LDW = BK + 4;   // 132 (Ws)
    __shared__ __align__(16) _Float16 As[64 * LDA];
    __shared__ __align__(16) _Float16 Ws[128 * LDW];
    __shared__ float s_sc[256], s_sh[256];
    const int tid = threadIdx.x;
    const int lane = tid & 63;
    const int wave = tid >> 6;
    const int wr = wave >> 1;   // rows wr*32
    const int wc = wave & 1;    // cols wc*64
    const int lm = lane & 15, lq = lane >> 4;
    const int mB = blockIdx.x * 64;
    const int n0 = wc * 64;

    // inline BN finalize: thread t reduces stripes for col t (coalesced)
    {
        float s = 0.f, q = 0.f;
        for (int st = 0; st < NSTRIPE; st++) {
            s += csumIn[st * 256 + tid];
            q += csqIn[st * 256 + tid];
        }
        float invM = 1.0f / (float)M;
        float mean = s * invM;
        float var = q * invM - mean * mean;
        float scv = g[tid] * rsqrtf(var + 1e-5f);
        s_sc[tid] = scv;
        s_sh[tid] = b[tid] - mean * scv;
    }
    __syncthreads();

    f4 acc[2][4];
#pragma unroll
    for (int i = 0; i < 2; i++)
#pragma unroll
        for (int j = 0; j < 4; j++) acc[i][j] = (f4){0.f, 0.f, 0.f, 0.f};

    const int sr = tid >> 4;
    const int sc = (tid & 15) * 8;

    for (int kc = 0; kc < K; kc += BK) {
        if (kc) __syncthreads();
        float bscv[8], bshv[8];
#pragma unroll
        for (int e = 0; e < 8; e++) {
            bscv[e] = s_sc[kc + sc + e];
            bshv[e] = s_sh[kc + sc + e];
        }
#pragma unroll
        for (int rr = 0; rr < 64; rr += 16) {
            int gr = mB + rr + sr; if (gr >= M) gr = M - 1;
            h8 h = *(const h8*)&A[(size_t)gr * K + kc + sc];
#pragma unroll
            for (int e = 0; e < 8; e++)
                h[e] = (_Float16)fmaxf((float)h[e] * bscv[e] + bshv[e], 0.f);
            *(h8*)&As[(rr + sr) * LDA + sc] = h;
        }
#pragma unroll
        for (int rr = 0; rr < 128; rr += 16)
            *(h8*)&Ws[(rr + sr) * LDW + sc] =
                *(const h8*)&Wt[(size_t)(rr + sr) * K + kc + sc];
        __syncthreads();
#pragma unroll
        for (int ks = 0; ks < BK / 32; ks++) {
            h8 af[2], bf[4];
#pragma unroll
            for (int i = 0; i < 2; i++)
                af[i] = *(const h8*)&As[(wr * 32 + i * 16 + lm) * LDA + ks * 32 + lq * 8];
#pragma unroll
            for (int j = 0; j < 4; j++)
                bf[j] = *(const h8*)&Ws[(n0 + j * 16 + lm) * LDW + ks * 32 + lq * 8];
#pragma unroll
            for (int i = 0; i < 2; i++)
#pragma unroll
                for (int j = 0; j < 4; j++)
                    acc[i][j] = __builtin_amdgcn_mfma_f32_16x16x32_f16(af[i], bf[j], acc[i][j], 0, 0, 0);
        }
    }

    float bv[4];
#pragma unroll
    for (int j = 0; j < 4; j++) bv[j] = bias[n0 + j * 16 + lm];
    float ls[4] = {0, 0, 0, 0}, lsq[4] = {0, 0, 0, 0};
    __syncthreads();
    _Float16* Cs = As;
#pragma unroll
    for (int i = 0; i < 2; i++) {
        int row = wr * 32 + i * 16 + lq * 4;
        bool rv[4];
#pragma unroll
        for (int r = 0; r < 4; r++) rv[r] = (mB + row + r) < M;
#pragma unroll
        for (int j = 0; j < 4; j++) {
#pragma unroll
            for (int r = 0; r < 4; r++) {
                float v = acc[i][j][r] + bv[j];
                Cs[(row + r) * LDA + wc * 64 + j * 16 + lm] = (_Float16)v;
                if (rv[r]) { ls[j] += v; lsq[j] += v * v; }
            }
        }
    }
    const int stripe = blockIdx.x & (NSTRIPE - 1);
#pragma unroll
    for (int j = 0; j < 4; j++) {
        float s = ls[j], q = lsq[j];
        s += __shfl_xor(s, 16); s += __shfl_xor(s, 32);
        q += __shfl_xor(q, 16); q += __shfl_xor(q, 32);
        if (lq == 0) {
            atomicAdd(&csum[stripe * NCF + n0 + j * 16 + lm], s);
            atomicAdd(&csq[stripe * NCF + n0 + j * 16 + lm], q);
        }
    }
    __syncthreads();
    const int trow = tid >> 4;
    const int tcol = (tid & 15) * 8;
#pragma unroll
    for (int p = 0; p < 4; p++) {
        int row = p * 16 + trow;
        int grow = mB + row;
        if (grow < M) {
            h8 v = *(const h8*)&Cs[row * LDA + tcol];
            *(h8*)&C[(size_t)grow * NCF + tcol] = v;
        }
    }
}

// ---- BN apply + relu (+optional vn-add after relu), f16 io, f32 math ----
__global__ void bnrelu_k(const _Float16* __restrict__ in, _Float16* __restrict__ out,
                         const float* __restrict__ csum, const float* __restrict__ csq,
                         const float* __restrict__ g, const float* __restrict__ b,
                         const _Float16* __restrict__ vfeat, const int* __restrict__ batch,
                         int M) {
    constexpr int PER = 16;
    __shared__ float s_sc[128], s_sh[128];
    if (threadIdx.x < 128) {
        int col = threadIdx.x;
        float s = 0.f, q = 0.f;
        for (int st = 0; st < NSTRIPE; st++) {
            s += csum[st * 128 + col];
            q += csq[st * 128 + col];
        }
        float invM = 1.0f / (float)M;
        float mean = s * invM;
        float var = q * invM - mean * mean;
        float scv = g[col] * rsqrtf(var + 1e-5f);
        s_sc[col] = scv;
        s_sh[col] = b[col] - mean * scv;
    }
    __syncthreads();
    int tid = blockIdx.x * blockDim.x + threadIdx.x;
    int c8 = tid % PER;
    int c0 = c8 * 8;
    float sc[8], sh[8];
#pragma unroll
    for (int e = 0; e < 8; e++) { sc[e] = s_sc[c0 + e]; sh[e] = s_sh[c0 + e]; }
    int total = M * PER;
    int stride = gridDim.x * blockDim.x;
    for (int i = tid; i < total; i += stride) {
        int row = i / PER;
        h8 u = ((const h8*)in)[i];
        h8 w;
        bool vn = (vfeat != nullptr);
        if (vn) w = ((const h8*)vfeat)[batch[row] * PER + c8];
        h8 o;
#pragma unroll
        for (int e = 0; e < 8; e++) {
            float vv = fmaxf((float)u[e] * sc[e] + sh[e], 0.f);
            if (vn) vv += (float)w[e];
            o[e] = (_Float16)vv;
        }
        ((h8*)out)[i] = o;
    }
}

// ---- BN apply + segment-sum pool over sorted batch (NC=128) -------------
__global__ __launch_bounds__(256) void bnpool_k(
        const _Float16* __restrict__ in, _Float16* __restrict__ out,
        const float* __restrict__ csum, const float* __restrict__ csq,
        const float* __restrict__ g, const float* __restrict__ b,
        const int* __restrict__ batch, float* __restrict__ pooled,
        int M, int relu) {
    __shared__ float s_sc[128], s_sh[128];
    if (threadIdx.x < 128) {
        int col = threadIdx.x;
        float s = 0.f, q = 0.f;
        for (int st = 0; st < NSTRIPE; st++) {
            s += csum[st * 128 + col];
            q += csq[st * 128 + col];
        }
        float invM = 1.0f / (float)M;
        float mean = s * invM;
        float var = q * invM - mean * mean;
        float scv = g[col] * rsqrtf(var + 1e-5f);
        s_sc[col] = scv;
        s_sh[col] = b[col] - mean * scv;
    }
    __syncthreads();
    int t = threadIdx.x;
    int c0 = (t & 63) * 2;
    int r0 = blockIdx.x * 128 + (t >> 6) * 32;
    float sc0 = s_sc[c0], h0 = s_sh[c0];
    float sc1 = s_sc[c0 + 1], h1 = s_sh[c0 + 1];
    int rend = r0 + 32; if (rend > M) rend = M;
    float a0 = 0.f, a1 = 0.f; int cur = -1;
    int r = r0;
    for (; r + 1 < rend; r += 2) {
        h2 ua = ((const h2*)in)[(size_t)r * 64 + (c0 >> 1)];
        h2 ub = ((const h2*)in)[(size_t)(r + 1) * 64 + (c0 >> 1)];
        int bga = batch[r], bgb = batch[r + 1];
        float va0 = (float)ua.x * sc0 + h0, va1 = (float)ua.y * sc1 + h1;
        float vb0 = (float)ub.x * sc0 + h0, vb1 = (float)ub.y * sc1 + h1;
        if (relu) {
            va0 = fmaxf(va0, 0.f); va1 = fmaxf(va1, 0.f);
            vb0 = fmaxf(vb0, 0.f); vb1 = fmaxf(vb1, 0.f);
        }
        if (out) {
            h2 oa; oa.x = (_Float16)va0; oa.y = (_Float16)va1;
            h2 ob; ob.x = (_Float16)vb0; ob.y = (_Float16)vb1;
            ((h2*)out)[(size_t)r * 64 + (c0 >> 1)] = oa;
            ((h2*)out)[(size_t)(r + 1) * 64 + (c0 >> 1)] = ob;
        }
        if (bga != cur) {
            if (cur >= 0) {
                atomicAdd(&pooled[(size_t)cur * DH + c0], a0);
                atomicAdd(&pooled[(size_t)cur * DH + c0 + 1], a1);
            }
            cur = bga; a0 = 0.f; a1 = 0.f;
        }
        a0 += va0; a1 += va1;
        if (bgb != cur) {
            atomicAdd(&pooled[(size_t)cur * DH + c0], a0);
            atomicAdd(&pooled[(size_t)cur * DH + c0 + 1], a1);
            cur = bgb; a0 = 0.f; a1 = 0.f;
        }
        a0 += vb0; a1 += vb1;
    }
    for (; r < rend; r++) {
        h2 u = ((const h2*)in)[(size_t)r * 64 + (c0 >> 1)];
        float v0 = (float)u.x * sc0 + h0;
        float v1 = (float)u.y * sc1 + h1;
        if (relu) { v0 = fmaxf(v0, 0.f); v1 = fmaxf(v1, 0.f); }
        if (out) { h2 o; o.x = (_Float16)v0; o.y = (_Float16)v1; ((h2*)out)[(size_t)r * 64 + (c0 >> 1)] = o; }
        int bg = batch[r];
        if (bg != cur) {
            if (cur >= 0) {
                atomicAdd(&pooled[(size_t)cur * DH + c0], a0);
                atomicAdd(&pooled[(size_t)cur * DH + c0 + 1], a1);
            }
            cur = bg; a0 = 0.f; a1 = 0.f;
        }
        a0 += v0; a1 += v1;
    }
    if (cur >= 0) {
        atomicAdd(&pooled[(size_t)cur * DH + c0], a0);
        atomicAdd(&pooled[(size_t)cur * DH + c0 + 1], a1);
    }
}

// ------------------------------------------------------------------------
extern "C" void kernel_launch(void* const* d_in, const int* in_sizes, int n_in,
                              void* d_out, int out_size, void* d_ws, size_t ws_size,
                              hipStream_t stream) {
    const float* x      = (const float*)d_in[0];
    const int*   ei     = (const int*)d_in[1];
    const int*   batch  = (const int*)d_in[2];
    const float* vn_emb = (const float*)d_in[3];
    const float* c1_W1  = (const float*)d_in[4];
    const float* c1_b1  = (const float*)d_in[5];
    const float* c1_bng = (const float*)d_in[6];
    const float* c1_bnb = (const float*)d_in[7];
    const float* c1_W2  = (const float*)d_in[8];
    const float* c1_b2  = (const float*)d_in[9];
    const float* bn1_g  = (const float*)d_in[10];
    const float* bn1_b  = (const float*)d_in[11];
    const float* cW1    = (const float*)d_in[12];
    const float* cb1    = (const float*)d_in[13];
    const float* cbng   = (const float*)d_in[14];
    const float* cbnb   = (const float*)d_in[15];
    const float* cW2    = (const float*)d_in[16];
    const float* cb2    = (const float*)d_in[17];
    const float* bns_g  = (const float*)d_in[18];
    const float* bns_b  = (const float*)d_in[19];
    const float* vW1    = (const float*)d_in[20];
    const float* vb1    = (const float*)d_in[21];
    const float* vbn1_g = (const float*)d_in[22];
    const float* vbn1_b = (const float*)d_in[23];
    const float* vW2    = (const float*)d_in[24];
    const float* vb2    = (const float*)d_in[25];
    const float* vbn2_g = (const float*)d_in[26];
    const float* vbn2_b = (const float*)d_in[27];
    float* outp = (float*)d_out;
    (void)in_sizes; (void)n_in; (void)out_size; (void)ws_size;

    char* w = (char*)d_ws;
    size_t off = 0;
    auto carve = [&](size_t bytes) -> void* {
        void* p = w + off; off = align256(off + bytes); return p;
    };
    // zero-init region
    int*   cursor  = (int*)carve((size_t)4 * NN * 4);   // 4-way striped
    float* pooled  = (float*)carve((size_t)NG * DH * 4);
    float* pooled2 = (float*)carve((size_t)NG * DH * 4);
    float *sA[3], *qA[3], *sB[3], *qB[3], *sV1, *qV1, *sV2, *qV2;
    for (int i = 0; i < 3; i++) {
        sA[i] = (float*)carve((size_t)NSTRIPE * 256 * 4);
        qA[i] = (float*)carve((size_t)NSTRIPE * 256 * 4);
    }
    for (int i = 0; i < 3; i++) {
        sB[i] = (float*)carve((size_t)NSTRIPE * 128 * 4);
        qB[i] = (float*)carve((size_t)NSTRIPE * 128 * 4);
    }
    sV1 = (float*)carve((size_t)NSTRIPE * 256 * 4);
    qV1 = (float*)carve((size_t)NSTRIPE * 256 * 4);
    sV2 = (float*)carve((size_t)NSTRIPE * 128 * 4);
    qV2 = (float*)carve((size_t)NSTRIPE * 128 * 4);
    size_t zbytes = off;
    // non-zeroed region
    int*   gcnt    = (int*)carve((size_t)NG * 4);
    int*   rowptr  = (int*)carve((size_t)(NN + 1) * 4);
    int*   rowbase = (int*)carve((size_t)4 * NN * 4);
    int*   slot    = (int*)carve((size_t)NE * 4);
    int*   esrc    = (int*)carve((size_t)NE * 4);
    int*   part    = (int*)carve((size_t)SCB * 4);
    _Float16* vfeat = (_Float16*)carve((size_t)NG * DH * 2);
    _Float16* zin   = (_Float16*)carve((size_t)NG * DH * 2);
    _Float16* zb    = (_Float16*)carve((size_t)NG * DH2 * 2);
    _Float16* vraw  = (_Float16*)carve((size_t)NG * DH * 2);
    _Float16* xh    = (_Float16*)carve((size_t)NN * DH * 2);
    _Float16* hb    = (_Float16*)carve((size_t)NN * DH * 2);
    _Float16* b1    = (_Float16*)carve((size_t)NN * DH2 * 2);
    _Float16* abuf  = (_Float16*)carve((size_t)NN * DH * 2);
    _Float16* Wt[8];
    for (int i = 0; i < 8; i++) Wt[i] = (_Float16*)carve((size_t)DH * DH2 * 2);

    WPack wp;
    wp.w[0] = c1_W1;            wp.K[0] = 128; wp.N[0] = 256;
    wp.w[1] = c1_W2;            wp.K[1] = 256; wp.N[1] = 128;
    wp.w[2] = cW1;              wp.K[2] = 128; wp.N[2] = 256;
    wp.w[3] = cW2;              wp.K[3] = 256; wp.N[3] = 128;
    wp.w[4] = cW1 + 128 * 256;  wp.K[4] = 128; wp.N[4] = 256;
    wp.w[5] = cW2 + 256 * 128;  wp.K[5] = 256; wp.N[5] = 128;
    wp.w[6] = vW1;              wp.K[6] = 128; wp.N[6] = 256;
    wp.w[7] = vW2;              wp.K[7] = 256; wp.N[7] = 128;
    for (int i = 0; i < 8; i++) wp.wt[i] = Wt[i];

    const int GB64 = (NN + 63) / 64;   // 1563
    const int GB   = (NN + 127) / 128; // 782 (bnpool grid)
    const int GV64 = (NG + 63) / 64;   // 8

    hipMemsetAsync(d_ws, 0, zbytes, stream);
    csrcast_k<<<EB4 + CB + WB, 256, 0, stream>>>(ei, cursor, slot, x, xh, vn_emb, vfeat, wp);
    scan1_k<<<SCB, 256, 0, stream>>>(cursor, part);
    scan2_k<<<1, 256, 0, stream>>>(part, rowptr, batch, gcnt);
    scan3_k<<<SCB, 256, 0, stream>>>(cursor, part, rowptr, rowbase);
    place_k<<<EB4, 256, 0, stream>>>(ei, rowbase, slot, esrc);

    // ---- layer 1 ----
    agg_k<<<NN / 4, 256, 0, stream>>>(xh, rowptr, esrc, hb);
    gemmA_k<<<GB64, 256, 0, stream>>>(hb, Wt[0], c1_b1, b1, sA[0], qA[0], NN);
    gemmB_k<<<GB64, 256, 0, stream>>>(b1, Wt[1], c1_b2, abuf, sB[0], qB[0], NN,
                                      sA[0], qA[0], c1_bng, c1_bnb);
    bnrelu_k<<<2048, 256, 0, stream>>>(abuf, abuf, sB[0], qB[0], bn1_g, bn1_b,
                                       vfeat, batch, NN);

    // ---- layer 2 ----
    agg_k<<<NN / 4, 256, 0, stream>>>(abuf, rowptr, esrc, hb);
    gemmA_k<<<GB64, 256, 0, stream>>>(hb, Wt[2], cb1, b1, sA[1], qA[1], NN);
    gemmB_k<<<GB64, 256, 0, stream>>>(b1, Wt[3], cb2, abuf, sB[1], qB[1], NN,
                                      sA[1], qA[1], cbng, cbnb);
    bnpool_k<<<GB, 256, 0, stream>>>(abuf, abuf, sB[1], qB[1], bns_g, bns_b,
                                     batch, pooled, NN, 1);

    // ---- virtual-node MLP (M = 512) ----
    zin_k<<<(NG * DH + 255) / 256, 256, 0, stream>>>(pooled, vfeat, zin);
    gemmA_k<<<GV64, 256, 0, stream>>>(zin, Wt[6], vb1, zb, sV1, qV1, NG);
    gemmB_k<<<GV64, 256, 0, stream>>>(zb, Wt[7], vb2, vraw, sV2, qV2, NG,
                                      sV1, qV1, vbn1_g, vbn1_b);
    bnrelu_k<<<32, 256, 0, stream>>>(vraw, vfeat, sV2, qV2, vbn2_g, vbn2_b,
                                     nullptr, nullptr, NG);

    // ---- layer 3 (vn-add as separate streaming pass) ----
    addvn_k<<<(NN * 16 + 255) / 256, 256, 0, stream>>>(abuf, vfeat, batch);
    agg_k<<<NN / 4, 256, 0, stream>>>(abuf, rowptr, esrc, hb);
    gemmA_k<<<GB64, 256, 0, stream>>>(hb, Wt[4], cb1 + 256, b1, sA[2], qA[2], NN);
    gemmB_k<<<GB64, 256, 0, stream>>>(b1, Wt[5], cb2 + 128, abuf, sB[2], qB[2], NN,
                                      sA[2], qA[2], cbng + 256, cbnb + 256);
    bnpool_k<<<GB, 256, 0, stream>>>(abuf, nullptr, sB[2], qB[2],
                                     bns_g + 128, bns_b + 128, batch, pooled2, NN, 0);

    finalout_k<<<(NG * DH + 255) / 256, 256, 0, stream>>>(pooled2, gcnt, outp);
}